// Round 1
// baseline (8397.489 us; speedup 1.0000x reference)
//
#include <hip/hip_runtime.h>

namespace {

constexpr int kN  = 32;
constexpr int kC  = 512;
constexpr int kH  = 32;
constexpr int kW  = 32;
constexpr int kHW = kH * kW;
constexpr int TAPS = 9;

constexpr int CI_CHUNK = 32;
constexpr int CO_TILE  = 128;
constexpr int SP_TILE  = 64;  // 2 rows of 32

constexpr size_t WT_ELEMS  = (size_t)TAPS * kC * kC;  // 2,359,296 floats
constexpr size_t QKV_ELEMS = (size_t)kN * kHW * kC;   // 16,777,216 floats

// ---------------- weight transpose: w[co][ci][ky][kx] -> wt[t][ci][co] -----
__global__ __launch_bounds__(256) void wt_transpose_kernel(
    const float* __restrict__ w, float* __restrict__ wt) {
  __shared__ float tile[32][289];  // [co][ci*9+t], stride 289 (odd)
  const int co0 = blockIdx.x * 32;
  const int ci0 = blockIdx.y * 32;
  for (int idx = threadIdx.x; idx < 32 * 288; idx += 256) {
    int c = idx % 288, r = idx / 288;
    tile[r][c] = w[(size_t)(co0 + r) * (kC * TAPS) + (size_t)ci0 * TAPS + c];
  }
  __syncthreads();
  for (int idx = threadIdx.x; idx < TAPS * 32 * 32; idx += 256) {
    int co = idx & 31;
    int rest = idx >> 5;      // 0..287
    int ci = rest & 31;
    int t  = rest >> 5;       // 0..8
    wt[((size_t)t * kC + ci0 + ci) * kC + co0 + co] = tile[co][ci * TAPS + t];
  }
}

// ---------------- conv3x3 as shift-GEMM ------------------------------------
// VAR 0: input NCHW (x), output NHWC (y[i][p][c])
// VAR 1: input NHWC (virt_n), output NCHW d_out with residual add of x (NCHW)
template <int VAR>
__global__ __launch_bounds__(256) void conv3x3_kernel(
    const float* __restrict__ xin, const float* __restrict__ wt,
    const float* __restrict__ xres, float* __restrict__ out) {
  __shared__ __align__(16) float xs[CI_CHUNK * 145];       // [ci][r*36+c], stride 145
  __shared__ __align__(16) float wsl[CI_CHUNK * CO_TILE];  // [ci][co] (reused as transpose buf)
  const int tid = threadIdx.x;
  const int tx = tid & 15;
  const int ty = tid >> 4;
  const int co0 = blockIdx.x * CO_TILE;
  const int h0  = blockIdx.y * 2;
  const int sp0 = h0 * kW;
  const int n   = blockIdx.z;

  float acc[4][8];
#pragma unroll
  for (int s = 0; s < 4; ++s)
#pragma unroll
    for (int j = 0; j < 8; ++j) acc[s][j] = 0.f;

  for (int ci0 = 0; ci0 < kC; ci0 += CI_CHUNK) {
    __syncthreads();  // protect xs from previous iteration's readers
    if (VAR == 0) {
      for (int idx = tid; idx < CI_CHUNK * 4 * 34; idx += 256) {
        int c = idx % 34;
        int rest = idx / 34;
        int r = rest & 3;
        int ci = rest >> 2;
        int row = h0 - 1 + r, col = c - 1;
        float v = 0.f;
        if ((unsigned)row < (unsigned)kH && (unsigned)col < (unsigned)kW)
          v = xin[(((size_t)n * kC + ci0 + ci) * kH + row) * kW + col];
        xs[ci * 145 + r * 36 + c] = v;
      }
    } else {
      for (int idx = tid; idx < CI_CHUNK * 4 * 34; idx += 256) {
        int ci = idx & 31;
        int rest = idx >> 5;
        int c = rest % 34;
        int r = rest / 34;
        int row = h0 - 1 + r, col = c - 1;
        float v = 0.f;
        if ((unsigned)row < (unsigned)kH && (unsigned)col < (unsigned)kW)
          v = xin[((size_t)n * kHW + row * kW + col) * kC + ci0 + ci];
        xs[ci * 145 + r * 36 + c] = v;
      }
    }
    for (int t = 0; t < TAPS; ++t) {
      __syncthreads();  // wsl safe to overwrite / xs writes done (t==0)
      {
        const float4* src = reinterpret_cast<const float4*>(
            wt + ((size_t)t * kC + ci0) * kC + co0);
        float4* dst = reinterpret_cast<float4*>(wsl);
#pragma unroll
        for (int rep = 0; rep < 4; ++rep) {
          int e = tid + rep * 256;
          int ci = e >> 5;
          int cof = e & 31;
          dst[ci * (CO_TILE / 4) + cof] = src[(size_t)ci * (kC / 4) + cof];
        }
      }
      __syncthreads();
      const int r  = (ty >> 3) + t / 3;          // slab row for this tap
      const int cb = (ty & 7) * 4 + t % 3;       // slab col base for this tap
      const float* xrow = &xs[r * 36 + cb];
      const float* wrow = &wsl[tx * 8];
#pragma unroll
      for (int ci = 0; ci < CI_CHUNK; ++ci) {
        float aa[4];
        aa[0] = xrow[ci * 145 + 0];
        aa[1] = xrow[ci * 145 + 1];
        aa[2] = xrow[ci * 145 + 2];
        aa[3] = xrow[ci * 145 + 3];
        const float4 b0 = *reinterpret_cast<const float4*>(&wrow[ci * CO_TILE]);
        const float4 b1 = *reinterpret_cast<const float4*>(&wrow[ci * CO_TILE + 4]);
        float bb[8] = {b0.x, b0.y, b0.z, b0.w, b1.x, b1.y, b1.z, b1.w};
#pragma unroll
        for (int s = 0; s < 4; ++s)
#pragma unroll
          for (int j = 0; j < 8; ++j) acc[s][j] = fmaf(aa[s], bb[j], acc[s][j]);
      }
    }
  }

  if (VAR == 0) {
    // NHWC store: y[n][sp][co], coalesced along co
#pragma unroll
    for (int s = 0; s < 4; ++s) {
      size_t o = ((size_t)n * kHW + sp0 + ty * 4 + s) * kC + co0 + tx * 8;
      float4 v0 = {acc[s][0], acc[s][1], acc[s][2], acc[s][3]};
      float4 v1 = {acc[s][4], acc[s][5], acc[s][6], acc[s][7]};
      *reinterpret_cast<float4*>(&out[o]) = v0;
      *reinterpret_cast<float4*>(&out[o + 4]) = v1;
    }
  } else {
    // transpose 64sp x 128co tile through LDS in 32-co quarters,
    // add residual, store NCHW coalesced along spatial
    for (int qd = 0; qd < 4; ++qd) {
      __syncthreads();
      if ((tx >> 2) == qd) {
        int coL = (tx & 3) * 8;
#pragma unroll
        for (int s = 0; s < 4; ++s)
#pragma unroll
          for (int j = 0; j < 8; ++j)
            wsl[(coL + j) * 65 + ty * 4 + s] = acc[s][j];
      }
      __syncthreads();
#pragma unroll
      for (int kk = 0; kk < 8; ++kk) {
        int coL = (tid >> 6) + kk * 4;
        int spp = tid & 63;
        int co = co0 + qd * 32 + coL;
        size_t o = ((size_t)n * kC + co) * kHW + sp0 + spp;
        out[o] = wsl[coL * 65 + spp] + xres[o];
      }
    }
  }
}

// ---------------- fused per-pixel attention: QK^T -> softmax -> PV ---------
// q,k,v,virt all NHWC-style [i][p][c]; virt aliases q (block p owns position p)
__global__ __launch_bounds__(256) void attn_kernel(
    const float* q, const float* __restrict__ k,
    const float* __restrict__ v, float* virt) {
  __shared__ float Qs[32 * 66];
  __shared__ float Ks[32 * 66];
  __shared__ float Ps[32 * 36];
  const int p = blockIdx.x;
  const int tid = threadIdx.x;
  const int i  = tid >> 3;         // 0..31 query instance
  const int j0 = (tid & 7) * 4;    // 4 key instances per thread
  float acc[4] = {0.f, 0.f, 0.f, 0.f};

  for (int c0 = 0; c0 < kC; c0 += 64) {
    __syncthreads();
    for (int idx = tid; idx < 32 * 64; idx += 256) {
      int c = idx & 63, r = idx >> 6;
      size_t g = ((size_t)r * kHW + p) * kC + c0 + c;
      Qs[r * 66 + c] = q[g];
      Ks[r * 66 + c] = k[g];
    }
    __syncthreads();
#pragma unroll
    for (int c = 0; c < 64; ++c) {
      float qa = Qs[i * 66 + c];
      acc[0] = fmaf(qa, Ks[(j0 + 0) * 66 + c], acc[0]);
      acc[1] = fmaf(qa, Ks[(j0 + 1) * 66 + c], acc[1]);
      acc[2] = fmaf(qa, Ks[(j0 + 2) * 66 + c], acc[2]);
      acc[3] = fmaf(qa, Ks[(j0 + 3) * 66 + c], acc[3]);
    }
  }
  constexpr float scale = 0.044194173824159216f;  // 1/sqrt(512)
#pragma unroll
  for (int jj = 0; jj < 4; ++jj) acc[jj] *= scale;
  // softmax over j: reduce across the 8 lanes sharing instance i
  float m = fmaxf(fmaxf(acc[0], acc[1]), fmaxf(acc[2], acc[3]));
  for (int off = 1; off < 8; off <<= 1) m = fmaxf(m, __shfl_xor(m, off));
  float e[4];
  float s = 0.f;
#pragma unroll
  for (int jj = 0; jj < 4; ++jj) {
    e[jj] = __expf(acc[jj] - m);
    s += e[jj];
  }
  for (int off = 1; off < 8; off <<= 1) s += __shfl_xor(s, off);
  const float inv = 1.f / s;
#pragma unroll
  for (int jj = 0; jj < 4; ++jj) Ps[i * 36 + j0 + jj] = e[jj] * inv;

  // PV: virt[i][p][c] = sum_j P[i][j] * v[j][p][c]
  const int c_ = tid & 63;
  const int i4 = tid >> 6;
  for (int c0 = 0; c0 < kC; c0 += 64) {
    __syncthreads();  // also publishes Ps on first iteration
    for (int idx = tid; idx < 32 * 64; idx += 256) {
      int c = idx & 63, r = idx >> 6;
      Qs[r * 66 + c] = v[((size_t)r * kHW + p) * kC + c0 + c];  // reuse Qs as Vs
    }
    __syncthreads();
#pragma unroll
    for (int it = 0; it < 8; ++it) {
      const int ii = i4 + it * 4;
      float o = 0.f;
#pragma unroll
      for (int j = 0; j < 32; ++j)
        o = fmaf(Ps[ii * 36 + j], Qs[j * 66 + c_], o);
      virt[((size_t)ii * kHW + p) * kC + c0 + c_] = o;
    }
  }
}

// ---------------- GroupNorm(1,C) stats per instance ------------------------
__global__ __launch_bounds__(1024) void gn_stats_kernel(
    const float* __restrict__ virt, float* __restrict__ stats) {
  const int i = blockIdx.x;
  const float4* src = reinterpret_cast<const float4*>(virt + (size_t)i * kHW * kC);
  constexpr int NV = kHW * kC / 4;
  float s = 0.f, sq = 0.f;
  for (int idx = threadIdx.x; idx < NV; idx += 1024) {
    float4 vv = src[idx];
    s += vv.x + vv.y + vv.z + vv.w;
    sq = fmaf(vv.x, vv.x, sq);
    sq = fmaf(vv.y, vv.y, sq);
    sq = fmaf(vv.z, vv.z, sq);
    sq = fmaf(vv.w, vv.w, sq);
  }
  __shared__ float rs[16], rq[16];
  for (int off = 1; off < 64; off <<= 1) {
    s += __shfl_xor(s, off);
    sq += __shfl_xor(sq, off);
  }
  const int lane = threadIdx.x & 63;
  const int wid = threadIdx.x >> 6;
  if (lane == 0) { rs[wid] = s; rq[wid] = sq; }
  __syncthreads();
  if (threadIdx.x < 16) {
    s = rs[threadIdx.x];
    sq = rq[threadIdx.x];
    for (int off = 1; off < 16; off <<= 1) {
      s += __shfl_xor(s, off);
      sq += __shfl_xor(sq, off);
    }
    if (threadIdx.x == 0) {
      constexpr float invn = 1.f / ((float)kHW * kC);
      float mean = s * invn;
      float var = sq * invn - mean * mean;
      stats[i] = mean;
      stats[32 + i] = rsqrtf(var + 1e-5f);
    }
  }
}

// ---------------- GN apply + affine + ReLU ---------------------------------
__global__ __launch_bounds__(256) void gn_apply_kernel(
    const float* __restrict__ virt, const float* __restrict__ stats,
    const float* __restrict__ gamma, const float* __restrict__ beta,
    float* __restrict__ outn) {
  const size_t idx4 = (size_t)blockIdx.x * 256 + threadIdx.x;
  const int i  = (int)(idx4 >> 17);            // kHW*kC/4 = 131072 = 2^17
  const int c4 = (int)(idx4 & (kC / 4 - 1));
  const float mean = stats[i];
  const float rstd = stats[32 + i];
  const float4 g = reinterpret_cast<const float4*>(gamma)[c4];
  const float4 b = reinterpret_cast<const float4*>(beta)[c4];
  float4 vv = reinterpret_cast<const float4*>(virt)[idx4];
  vv.x = fmaxf(fmaf((vv.x - mean) * rstd, g.x, b.x), 0.f);
  vv.y = fmaxf(fmaf((vv.y - mean) * rstd, g.y, b.y), 0.f);
  vv.z = fmaxf(fmaf((vv.z - mean) * rstd, g.z, b.z), 0.f);
  vv.w = fmaxf(fmaf((vv.w - mean) * rstd, g.w, b.w), 0.f);
  reinterpret_cast<float4*>(outn)[idx4] = vv;
}

}  // namespace

extern "C" void kernel_launch(void* const* d_in, const int* in_sizes, int n_in,
                              void* d_out, int out_size, void* d_ws,
                              size_t ws_size, hipStream_t stream) {
  const float* x     = (const float*)d_in[0];
  const float* w_q   = (const float*)d_in[1];
  const float* w_k   = (const float*)d_in[2];
  const float* w_v   = (const float*)d_in[3];
  const float* w_o   = (const float*)d_in[4];
  const float* gamma = (const float*)d_in[5];
  const float* beta  = (const float*)d_in[6];
  float* out = (float*)d_out;

  float* ws   = (float*)d_ws;
  float* wt_q = ws;
  float* wt_k = wt_q + WT_ELEMS;
  float* wt_v = wt_k + WT_ELEMS;
  float* wt_o = wt_v + WT_ELEMS;
  float* qb    = wt_o + WT_ELEMS;
  float* kb    = qb + QKV_ELEMS;
  float* vb    = kb + QKV_ELEMS;
  float* stats = vb + QKV_ELEMS;  // 64 floats
  float* virt  = qb;              // q dead after attn phase 1 (per-position)
  float* virtn = kb;              // k dead after attn

  dim3 wtg(16, 16);
  wt_transpose_kernel<<<wtg, 256, 0, stream>>>(w_q, wt_q);
  wt_transpose_kernel<<<wtg, 256, 0, stream>>>(w_k, wt_k);
  wt_transpose_kernel<<<wtg, 256, 0, stream>>>(w_v, wt_v);
  wt_transpose_kernel<<<wtg, 256, 0, stream>>>(w_o, wt_o);

  dim3 cg(kC / CO_TILE, kHW / SP_TILE, kN);  // (4, 16, 32)
  conv3x3_kernel<0><<<cg, 256, 0, stream>>>(x, wt_q, nullptr, qb);
  conv3x3_kernel<0><<<cg, 256, 0, stream>>>(x, wt_k, nullptr, kb);
  conv3x3_kernel<0><<<cg, 256, 0, stream>>>(x, wt_v, nullptr, vb);

  attn_kernel<<<kHW, 256, 0, stream>>>(qb, kb, vb, virt);

  gn_stats_kernel<<<kN, 1024, 0, stream>>>(virt, stats);
  gn_apply_kernel<<<(int)(QKV_ELEMS / 4 / 256), 256, 0, stream>>>(
      virt, stats, gamma, beta, virtn);

  conv3x3_kernel<1><<<cg, 256, 0, stream>>>(virtn, wt_o, x, out);
}

// Round 3
// 1952.416 us; speedup vs baseline: 4.3011x; 4.3011x over previous
//
#include <hip/hip_runtime.h>

namespace {

constexpr int kN  = 32;
constexpr int kC  = 512;
constexpr int kH  = 32;
constexpr int kW  = 32;
constexpr int kHW = kH * kW;

// bf16 chunked-padded activation layout: [n][chunk=ci/32][34 rows][34 cols][32 ci]
constexpr int PCH   = 36992;                 // 34*34*32 elems per (n,chunk) plane
constexpr size_t WTF_ELEMS = (size_t)9 * kC * kC;          // 2,359,296 bf16
constexpr size_t XH_ELEMS  = (size_t)kN * 16 * PCH;        // 18,939,904 bf16
constexpr size_t QKV_ELEMS = (size_t)kN * kHW * kC;        // 16,777,216 bf16

using bf16x8 = __attribute__((ext_vector_type(8))) short;
using bf16x4 = __attribute__((ext_vector_type(4))) short;
using f32x4  = __attribute__((ext_vector_type(4))) float;

__device__ __forceinline__ float bf2f(short s) {
  unsigned u = ((unsigned)(unsigned short)s) << 16;
  return __builtin_bit_cast(float, u);
}
__device__ __forceinline__ short f2bf(float f) {
  unsigned u = __builtin_bit_cast(unsigned, f);
  u += 0x7FFFu + ((u >> 16) & 1u);
  return (short)(u >> 16);
}
__device__ __forceinline__ void gload_lds16(const void* g, void* l) {
  __builtin_amdgcn_global_load_lds(
      (const __attribute__((address_space(1))) void*)g,
      (__attribute__((address_space(3))) void*)l, 16, 0, 0);
}

// ---- weight pack: w[co][ci][3][3] f32 -> wtf[t][kk][nnG][lane][8] bf16 ----
// lane = (co&15) | (hi<<4), j = ci&7, hi = (ci>>3)&3, kk = ci>>5, nnG = co>>4
__global__ __launch_bounds__(256) void wtf_pack_kernel(
    const float* __restrict__ w, short* __restrict__ wtf) {
  __shared__ float tile[32][289];  // [co][ci*9+t]
  const int co0 = blockIdx.x * 32;
  const int ci0 = blockIdx.y * 32;
  for (int idx = threadIdx.x; idx < 32 * 288; idx += 256) {
    int c = idx % 288, r = idx / 288;
    tile[r][c] = w[(size_t)(co0 + r) * (kC * 9) + (size_t)ci0 * 9 + c];
  }
  __syncthreads();
  const int kkb  = ci0 >> 5;
  const int nnG0 = co0 >> 4;
  for (int g = threadIdx.x; g < 9 * 2 * 64; g += 256) {
    int laneg = g & 63;
    int nnL   = (g >> 6) & 1;
    int t     = g >> 7;  // 0..8
    int hi    = laneg >> 4;
    int coL   = nnL * 16 + (laneg & 15);
    bf16x8 pk;
#pragma unroll
    for (int j = 0; j < 8; ++j) pk[j] = f2bf(tile[coL][(hi * 8 + j) * 9 + t]);
    *(bf16x8*)&wtf[(((size_t)t * 16 + kkb) * 32 + nnG0 + nnL) * 512 + laneg * 8] = pk;
  }
}

// ---- x NCHW f32 -> xh chunked-padded bf16 ---------------------------------
__global__ __launch_bounds__(256) void x2xh_kernel(
    const float* __restrict__ x, short* __restrict__ xh) {
  __shared__ float tile[32][33];  // [w][ci]
  const int ch = blockIdx.x;   // 0..15
  const int h  = blockIdx.y;   // 0..31
  const int n  = blockIdx.z;   // 0..31
  const int w0 = threadIdx.x & 31;
  const int c0 = threadIdx.x >> 5;  // 8 ci rows per pass
#pragma unroll
  for (int pass = 0; pass < 4; ++pass) {
    int cir = pass * 8 + c0;
    tile[w0][cir] = x[(((size_t)n * kC + ch * 32 + cir) * kH + h) * kW + w0];
  }
  __syncthreads();
  // 256 threads = 32 w-positions x 4 ci-groups-of-8... NO: 8 groups of 4.
  // wv in 0..31, g4 in {0,4,...,28}: exactly covers ci 0..31, no OOB.
  const int wv = threadIdx.x >> 3;
  const int g4 = (threadIdx.x & 7) * 4;
  bf16x4 pk;
#pragma unroll
  for (int j = 0; j < 4; ++j) pk[j] = f2bf(tile[wv][g4 + j]);
  *(bf16x4*)&xh[(((size_t)n * 16 + ch) * 1156 + (size_t)(h + 1) * 34 + (wv + 1)) * 32 + g4] = pk;
}

// ---- conv3x3 via MFMA implicit shift-GEMM ---------------------------------
// xin: chunked-padded bf16; wtf: fragment-linear bf16
// EPI 0: out = bf16 NHWC [n][sp][co]
// EPI 1: out = f32 NCHW + residual xres (f32 NCHW)
template <int EPI>
__global__ __launch_bounds__(256, 3) void conv_mfma_kernel(
    const short* __restrict__ xin, const short* __restrict__ wtf,
    const float* __restrict__ xres, void* __restrict__ outp) {
  __shared__ __align__(16) short As[2][8192];  // [hi 4][pos 256][8] bf16 x2
  __shared__ __align__(16) short Bs[2][4096];  // [nnL 8][lane 64][8] bf16 x2
  const int tid  = threadIdx.x;
  const int lane = tid & 63;
  const int l15  = lane & 15, lhi = lane >> 4;
  const int wv   = tid >> 6;
  const int wm   = wv >> 1, wn = wv & 1;
  const int co0  = blockIdx.x * 128;
  const int sp0  = blockIdx.y * 128;
  const int h0   = blockIdx.y * 4;
  const int n    = blockIdx.z;

  const short* srcA = xin + (size_t)n * (16 * PCH) + (size_t)h0 * (34 * 32);
  const short* srcW = wtf + (size_t)(co0 >> 4) * 512;

  f32x4 acc[4][4];
#pragma unroll
  for (int mf = 0; mf < 4; ++mf)
#pragma unroll
    for (int nf = 0; nf < 4; ++nf)
#pragma unroll
      for (int r = 0; r < 4; ++r) acc[mf][nf][r] = 0.f;

  const int wbase  = tid & 192;
  const int pclamp = (tid < 204) ? tid : 0;

#define STAGE_A(kk, buf)                                                      \
  {                                                                           \
    const short* gA = srcA + (size_t)(kk) * PCH + pclamp * 32;                \
    _Pragma("unroll") for (int pass = 0; pass < 4; ++pass)                    \
        gload_lds16(gA + pass * 8, &As[buf][(pass * 256 + wbase) * 8]);       \
  }
#define STAGE_B(t, kk, buf)                                                   \
  {                                                                           \
    const short* gB = srcW + ((size_t)(t) * 16 + (kk)) * (32 * 512);          \
    _Pragma("unroll") for (int pass = 0; pass < 2; ++pass)                    \
        gload_lds16(gB + (size_t)(pass * 256 + tid) * 8,                      \
                    &Bs[buf][(pass * 256 + wbase) * 8]);                      \
  }

  STAGE_A(0, 0);
  STAGE_B(0, 0, 0);
  int ab = 0, bb = 0;
  for (int kk = 0; kk < 16; ++kk) {
#pragma unroll
    for (int t = 0; t < 9; ++t) {
      __syncthreads();  // staged buffers ready (barrier drains vmcnt)
      if (t < 8) {
        STAGE_B(t + 1, kk, bb ^ 1);
      } else if (kk < 15) {
        STAGE_B(0, kk + 1, bb ^ 1);
      }
      if (t == 4 && kk < 15) STAGE_A(kk + 1, ab ^ 1);
      const int dy = t / 3, dx = t % 3;  // compile-time (t unrolled)
      const int pb = (wm * 2 + dy) * 34 + l15 + dx;
      bf16x8 a[4], b[4];
#pragma unroll
      for (int mf = 0; mf < 4; ++mf)
        a[mf] = *(const bf16x8*)&As[ab][(lhi * 256 + pb + (mf >> 1) * 34 + (mf & 1) * 16) * 8];
#pragma unroll
      for (int nf = 0; nf < 4; ++nf)
        b[nf] = *(const bf16x8*)&Bs[bb][((wn * 4 + nf) * 64 + lane) * 8];
#pragma unroll
      for (int mf = 0; mf < 4; ++mf)
#pragma unroll
        for (int nf = 0; nf < 4; ++nf)
          acc[mf][nf] = __builtin_amdgcn_mfma_f32_16x16x32_bf16(
              a[mf], b[nf], acc[mf][nf], 0, 0, 0);
      bb ^= 1;
    }
    ab ^= 1;
  }
#undef STAGE_A
#undef STAGE_B

  if constexpr (EPI == 0) {
    short* out = (short*)outp;
#pragma unroll
    for (int mf = 0; mf < 4; ++mf)
#pragma unroll
      for (int r = 0; r < 4; ++r) {
        size_t off = ((size_t)n * kHW + sp0 + wm * 64 + mf * 16 + lhi * 4 + r) * kC
                     + co0 + wn * 64 + l15;
#pragma unroll
        for (int nf = 0; nf < 4; ++nf) out[off + nf * 16] = f2bf(acc[mf][nf][r]);
      }
  } else {
    float* out = (float*)outp;
    float* T = (float*)&As[0][0];  // 32 co x 128 sp, stride 129 (16.5 KB)
#pragma unroll 1
    for (int nf = 0; nf < 4; ++nf) {
      __syncthreads();
      const int coL = wn * 16 + l15;
#pragma unroll
      for (int mf = 0; mf < 4; ++mf)
#pragma unroll
        for (int r = 0; r < 4; ++r)
          T[coL * 129 + wm * 64 + mf * 16 + lhi * 4 + r] = acc[mf][nf][r];
      __syncthreads();
#pragma unroll
      for (int it = 0; it < 16; ++it) {
        int idx = it * 256 + tid;
        int c = idx >> 7, sp = idx & 127;
        int co = co0 + (c >> 4) * 64 + nf * 16 + (c & 15);
        size_t off = ((size_t)n * kC + co) * kHW + sp0 + sp;
        out[off] = T[c * 129 + sp] + xres[off];
      }
    }
  }
}

// ---- fused per-pixel attention (bf16 IO, fp32 LDS math) -------------------
__global__ __launch_bounds__(256) void attn_kernel(
    const short* q, const short* __restrict__ k,
    const short* __restrict__ v, short* virt) {
  __shared__ float Qs[32 * 66];
  __shared__ float Ks[32 * 66];
  __shared__ float Ps[32 * 36];
  const int p = blockIdx.x;
  const int tid = threadIdx.x;
  const int i  = tid >> 3;
  const int j0 = (tid & 7) * 4;
  float acc[4] = {0.f, 0.f, 0.f, 0.f};

  for (int c0 = 0; c0 < kC; c0 += 64) {
    __syncthreads();
    {
      int r = tid >> 3, c8 = (tid & 7) * 8;
      size_t g = ((size_t)r * kHW + p) * kC + c0 + c8;
      bf16x8 vq = *(const bf16x8*)&q[g];
      bf16x8 vk = *(const bf16x8*)&k[g];
#pragma unroll
      for (int jj = 0; jj < 8; ++jj) {
        Qs[r * 66 + c8 + jj] = bf2f(vq[jj]);
        Ks[r * 66 + c8 + jj] = bf2f(vk[jj]);
      }
    }
    __syncthreads();
#pragma unroll
    for (int c = 0; c < 64; ++c) {
      float qa = Qs[i * 66 + c];
      acc[0] = fmaf(qa, Ks[(j0 + 0) * 66 + c], acc[0]);
      acc[1] = fmaf(qa, Ks[(j0 + 1) * 66 + c], acc[1]);
      acc[2] = fmaf(qa, Ks[(j0 + 2) * 66 + c], acc[2]);
      acc[3] = fmaf(qa, Ks[(j0 + 3) * 66 + c], acc[3]);
    }
  }
  constexpr float scale = 0.044194173824159216f;  // 1/sqrt(512)
#pragma unroll
  for (int jj = 0; jj < 4; ++jj) acc[jj] *= scale;
  float m = fmaxf(fmaxf(acc[0], acc[1]), fmaxf(acc[2], acc[3]));
  for (int off = 1; off < 8; off <<= 1) m = fmaxf(m, __shfl_xor(m, off));
  float e[4];
  float s = 0.f;
#pragma unroll
  for (int jj = 0; jj < 4; ++jj) {
    e[jj] = __expf(acc[jj] - m);
    s += e[jj];
  }
  for (int off = 1; off < 8; off <<= 1) s += __shfl_xor(s, off);
  const float inv = 1.f / s;
#pragma unroll
  for (int jj = 0; jj < 4; ++jj) Ps[i * 36 + j0 + jj] = e[jj] * inv;

  const int c_ = tid & 63;
  const int i4 = tid >> 6;
  for (int c0 = 0; c0 < kC; c0 += 64) {
    __syncthreads();
    {
      int r = tid >> 3, c8 = (tid & 7) * 8;
      bf16x8 vv = *(const bf16x8*)&v[((size_t)r * kHW + p) * kC + c0 + c8];
#pragma unroll
      for (int jj = 0; jj < 8; ++jj) Qs[r * 66 + c8 + jj] = bf2f(vv[jj]);
    }
    __syncthreads();
#pragma unroll
    for (int it = 0; it < 8; ++it) {
      const int ii = i4 + it * 4;
      float o = 0.f;
#pragma unroll
      for (int j = 0; j < 32; ++j)
        o = fmaf(Ps[ii * 36 + j], Qs[j * 66 + c_], o);
      virt[((size_t)ii * kHW + p) * kC + c0 + c_] = f2bf(o);
    }
  }
}

// ---- GroupNorm(1,C) stats per instance ------------------------------------
__global__ __launch_bounds__(1024) void gn_stats_kernel(
    const short* __restrict__ virt, float* __restrict__ stats) {
  const int i = blockIdx.x;
  const short* src = virt + (size_t)i * kHW * kC;
  float s = 0.f, sq = 0.f;
  for (int idx = threadIdx.x; idx < kHW * kC / 8; idx += 1024) {
    bf16x8 vv = *(const bf16x8*)&src[(size_t)idx * 8];
#pragma unroll
    for (int jj = 0; jj < 8; ++jj) {
      float f = bf2f(vv[jj]);
      s += f;
      sq = fmaf(f, f, sq);
    }
  }
  __shared__ float rs[16], rq[16];
  for (int off = 1; off < 64; off <<= 1) {
    s += __shfl_xor(s, off);
    sq += __shfl_xor(sq, off);
  }
  const int lane = threadIdx.x & 63;
  const int wid = threadIdx.x >> 6;
  if (lane == 0) { rs[wid] = s; rq[wid] = sq; }
  __syncthreads();
  if (threadIdx.x < 16) {
    s = rs[threadIdx.x];
    sq = rq[threadIdx.x];
    for (int off = 1; off < 16; off <<= 1) {
      s += __shfl_xor(s, off);
      sq += __shfl_xor(sq, off);
    }
    if (threadIdx.x == 0) {
      constexpr float invn = 1.f / ((float)kHW * kC);
      float mean = s * invn;
      float var = sq * invn - mean * mean;
      stats[i] = mean;
      stats[32 + i] = rsqrtf(var + 1e-5f);
    }
  }
}

// ---- GN apply + affine + ReLU -> chunked-padded bf16 ----------------------
__global__ __launch_bounds__(256) void gn_apply_kernel(
    const short* __restrict__ virt, const float* __restrict__ stats,
    const float* __restrict__ gamma, const float* __restrict__ beta,
    short* __restrict__ vh) {
  const size_t g = (size_t)blockIdx.x * 256 + threadIdx.x;
  const int i    = (int)(g >> 16);
  const int rest = (int)(g & 65535);
  const int p    = rest >> 6;
  const int c8g  = rest & 63;
  const int ci   = c8g * 8;
  const float mean = stats[i];
  const float rstd = stats[32 + i];
  bf16x8 vv = *(const bf16x8*)&virt[((size_t)i * kHW + p) * kC + ci];
  const float4 ga = ((const float4*)gamma)[c8g * 2];
  const float4 gb = ((const float4*)gamma)[c8g * 2 + 1];
  const float4 ba = ((const float4*)beta)[c8g * 2];
  const float4 bb = ((const float4*)beta)[c8g * 2 + 1];
  const float gv[8] = {ga.x, ga.y, ga.z, ga.w, gb.x, gb.y, gb.z, gb.w};
  const float bv[8] = {ba.x, ba.y, ba.z, ba.w, bb.x, bb.y, bb.z, bb.w};
  bf16x8 o;
#pragma unroll
  for (int jj = 0; jj < 8; ++jj) {
    float f = (bf2f(vv[jj]) - mean) * rstd;
    f = fmaxf(fmaf(f, gv[jj], bv[jj]), 0.f);
    o[jj] = f2bf(f);
  }
  const size_t dst =
      (((size_t)i * 16 + (ci >> 5)) * 1156 + (size_t)((p >> 5) + 1) * 34 + (p & 31) + 1) * 32
      + (ci & 31);
  *(bf16x8*)&vh[dst] = o;
}

}  // namespace

extern "C" void kernel_launch(void* const* d_in, const int* in_sizes, int n_in,
                              void* d_out, int out_size, void* d_ws,
                              size_t ws_size, hipStream_t stream) {
  const float* x     = (const float*)d_in[0];
  const float* w_q   = (const float*)d_in[1];
  const float* w_k   = (const float*)d_in[2];
  const float* w_v   = (const float*)d_in[3];
  const float* w_o   = (const float*)d_in[4];
  const float* gamma = (const float*)d_in[5];
  const float* beta  = (const float*)d_in[6];

  short* ws    = (short*)d_ws;
  short* wtf_q = ws;
  short* wtf_k = wtf_q + WTF_ELEMS;
  short* wtf_v = wtf_k + WTF_ELEMS;
  short* wtf_o = wtf_v + WTF_ELEMS;
  short* xh    = wtf_o + WTF_ELEMS;
  short* vh    = xh + XH_ELEMS;
  short* qb    = vh + XH_ELEMS;
  short* kb    = qb + QKV_ELEMS;
  short* vb    = kb + QKV_ELEMS;
  float* stats = (float*)(vb + QKV_ELEMS);
  short* virt  = qb;  // attn writes per-position after reading q
  // zero halos of xh and vh (adjacent regions)
  hipMemsetAsync(xh, 0, (size_t)2 * XH_ELEMS * sizeof(short), stream);

  dim3 wg(16, 16);
  wtf_pack_kernel<<<wg, 256, 0, stream>>>(w_q, wtf_q);
  wtf_pack_kernel<<<wg, 256, 0, stream>>>(w_k, wtf_k);
  wtf_pack_kernel<<<wg, 256, 0, stream>>>(w_v, wtf_v);
  wtf_pack_kernel<<<wg, 256, 0, stream>>>(w_o, wtf_o);

  x2xh_kernel<<<dim3(16, 32, 32), 256, 0, stream>>>(x, xh);

  dim3 cg(4, 8, 32);  // co-tiles, sp-tiles(128), n
  conv_mfma_kernel<0><<<cg, 256, 0, stream>>>(xh, wtf_q, nullptr, qb);
  conv_mfma_kernel<0><<<cg, 256, 0, stream>>>(xh, wtf_k, nullptr, kb);
  conv_mfma_kernel<0><<<cg, 256, 0, stream>>>(xh, wtf_v, nullptr, vb);

  attn_kernel<<<kHW, 256, 0, stream>>>(qb, kb, vb, virt);

  gn_stats_kernel<<<kN, 1024, 0, stream>>>(virt, stats);
  gn_apply_kernel<<<(int)(QKV_ELEMS / 8 / 256), 256, 0, stream>>>(
      virt, stats, gamma, beta, vh);

  conv_mfma_kernel<1><<<cg, 256, 0, stream>>>(vh, wtf_o, x, (void*)d_out);
}

// Round 4
// 934.828 us; speedup vs baseline: 8.9829x; 2.0885x over previous
//
#include <hip/hip_runtime.h>

namespace {

constexpr int kN  = 32;
constexpr int kC  = 512;
constexpr int kH  = 32;
constexpr int kW  = 32;
constexpr int kHW = kH * kW;

// bf16 chunked-padded activation layout: [n][chunk=ci/32][34 rows][34 cols][32 ci]
constexpr int PCH   = 36992;                 // 34*34*32 elems per (n,chunk) plane
constexpr size_t WTF_ELEMS = (size_t)9 * kC * kC;          // 2,359,296 bf16
constexpr size_t XH_ELEMS  = (size_t)kN * 16 * PCH;        // 18,939,904 bf16
constexpr size_t QKV_ELEMS = (size_t)kN * kHW * kC;        // 16,777,216 bf16

using bf16x8 = __attribute__((ext_vector_type(8))) short;
using bf16x4 = __attribute__((ext_vector_type(4))) short;
using f32x4  = __attribute__((ext_vector_type(4))) float;

__device__ __forceinline__ float bf2f(short s) {
  unsigned u = ((unsigned)(unsigned short)s) << 16;
  return __builtin_bit_cast(float, u);
}
__device__ __forceinline__ short f2bf(float f) {
  unsigned u = __builtin_bit_cast(unsigned, f);
  u += 0x7FFFu + ((u >> 16) & 1u);
  return (short)(u >> 16);
}
__device__ __forceinline__ void gload_lds16(const void* g, void* l) {
  __builtin_amdgcn_global_load_lds(
      (const __attribute__((address_space(1))) void*)g,
      (__attribute__((address_space(3))) void*)l, 16, 0, 0);
}

// ---- weight pack: w[co][ci][3][3] f32 -> wtf[t][kk][nnG][lane][8] bf16 ----
// lane = (co&15) | (hi<<4), j = ci&7, hi = (ci>>3)&3, kk = ci>>5, nnG = co>>4
__global__ __launch_bounds__(256) void wtf_pack_kernel(
    const float* __restrict__ w, short* __restrict__ wtf) {
  __shared__ float tile[32][289];  // [co][ci*9+t]
  const int co0 = blockIdx.x * 32;
  const int ci0 = blockIdx.y * 32;
  for (int idx = threadIdx.x; idx < 32 * 288; idx += 256) {
    int c = idx % 288, r = idx / 288;
    tile[r][c] = w[(size_t)(co0 + r) * (kC * 9) + (size_t)ci0 * 9 + c];
  }
  __syncthreads();
  const int kkb  = ci0 >> 5;
  const int nnG0 = co0 >> 4;
  for (int g = threadIdx.x; g < 9 * 2 * 64; g += 256) {
    int laneg = g & 63;
    int nnL   = (g >> 6) & 1;
    int t     = g >> 7;  // 0..8
    int hi    = laneg >> 4;
    int coL   = nnL * 16 + (laneg & 15);
    bf16x8 pk;
#pragma unroll
    for (int j = 0; j < 8; ++j) pk[j] = f2bf(tile[coL][(hi * 8 + j) * 9 + t]);
    *(bf16x8*)&wtf[(((size_t)t * 16 + kkb) * 32 + nnG0 + nnL) * 512 + laneg * 8] = pk;
  }
}

// ---- x NCHW f32 -> xh chunked-padded bf16 ---------------------------------
__global__ __launch_bounds__(256) void x2xh_kernel(
    const float* __restrict__ x, short* __restrict__ xh) {
  __shared__ float tile[32][33];  // [w][ci]
  const int ch = blockIdx.x;   // 0..15
  const int h  = blockIdx.y;   // 0..31
  const int n  = blockIdx.z;   // 0..31
  const int w0 = threadIdx.x & 31;
  const int c0 = threadIdx.x >> 5;  // 8 ci rows per pass
#pragma unroll
  for (int pass = 0; pass < 4; ++pass) {
    int cir = pass * 8 + c0;
    tile[w0][cir] = x[(((size_t)n * kC + ch * 32 + cir) * kH + h) * kW + w0];
  }
  __syncthreads();
  // wv in 0..31, g4 in {0,4,...,28}: exactly covers ci 0..31, no OOB.
  const int wv = threadIdx.x >> 3;
  const int g4 = (threadIdx.x & 7) * 4;
  bf16x4 pk;
#pragma unroll
  for (int j = 0; j < 4; ++j) pk[j] = f2bf(tile[wv][g4 + j]);
  *(bf16x4*)&xh[(((size_t)n * 16 + ch) * 1156 + (size_t)(h + 1) * 34 + (wv + 1)) * 32 + g4] = pk;
}

// ---- conv3x3 via MFMA implicit shift-GEMM ---------------------------------
// A (activations) staged linearly in LDS, double-buffered per kk (1 barrier/kk).
// B (weights) loaded straight from global (fragment-linear wtf, L1/L2-hot).
// EPI 0: out = bf16 NHWC [n][sp][co]
// EPI 1: out = f32 NCHW + residual xres (f32 NCHW)
template <int EPI>
__global__ __launch_bounds__(256, 3) void conv_mfma_kernel(
    const short* __restrict__ xin, const short* __restrict__ wtf,
    const float* __restrict__ xres, void* __restrict__ outp) {
  __shared__ __align__(16) short As[2][8192];  // [pos 256][ci 32] bf16, x2
  const int tid  = threadIdx.x;
  const int lane = tid & 63;
  const int l15  = lane & 15, lhi = lane >> 4;
  const int wv   = tid >> 6;
  const int wm   = wv >> 1, wn = wv & 1;
  const int wbase = tid & 192;

  // XCD-chunked swizzle: 1024 blocks, 8 XCDs, 128/XCD = 4 full images.
  const int swz = ((blockIdx.x & 7) << 7) | (blockIdx.x >> 3);
  const int co0 = (swz & 3) * 128;
  const int spt = (swz >> 2) & 7;
  const int h0  = spt * 4;
  const int sp0 = spt * 128;
  const int n   = swz >> 5;

  const short* srcA = xin + (size_t)n * (16 * PCH) + (size_t)h0 * (34 * 32);
  // per-thread B pointer: frag-linear [t*16+kk][nnG][lane*8]
  const short* bptr = wtf + ((size_t)(co0 >> 4) + wn * 4) * 512 + lane * 8;

  f32x4 acc[4][4];
#pragma unroll
  for (int mf = 0; mf < 4; ++mf)
#pragma unroll
    for (int nf = 0; nf < 4; ++nf)
#pragma unroll
      for (int r = 0; r < 4; ++r) acc[mf][nf][r] = 0.f;

  // Linear stage: LDS mirrors the global 204*64B slab byte-for-byte.
  // (tail over-reads <3.3KB land in the adjacent allocated ws buffer; the
  //  corresponding LDS positions 204..255 are never read.)
#define STAGE_A(kk, buf)                                                      \
  {                                                                           \
    const short* gA = srcA + (size_t)(kk) * PCH;                              \
    _Pragma("unroll") for (int pass = 0; pass < 4; ++pass)                    \
        gload_lds16(gA + (size_t)(pass * 256 + tid) * 8,                      \
                    &As[buf][(pass * 256 + wbase) * 8]);                      \
  }

  STAGE_A(0, 0);
  __syncthreads();
  int ab = 0;
  for (int kk = 0; kk < 16; ++kk) {
    if (kk < 15) STAGE_A(kk + 1, ab ^ 1);
#pragma unroll
    for (int t = 0; t < 9; ++t) {
      const int dy = t / 3, dx = t % 3;  // compile-time (t unrolled)
      const short* bt = bptr + (size_t)(t * 16 + kk) * 16384;
      bf16x8 a[4], b[4];
#pragma unroll
      for (int nf = 0; nf < 4; ++nf)
        b[nf] = *(const bf16x8*)&bt[nf * 512];
#pragma unroll
      for (int mf = 0; mf < 4; ++mf) {
        const int pb = (wm * 2 + (mf >> 1) + dy) * 34 + (mf & 1) * 16 + l15 + dx;
        a[mf] = *(const bf16x8*)&As[ab][pb * 32 + lhi * 8];
      }
#pragma unroll
      for (int mf = 0; mf < 4; ++mf)
#pragma unroll
        for (int nf = 0; nf < 4; ++nf)
          acc[mf][nf] = __builtin_amdgcn_mfma_f32_16x16x32_bf16(
              a[mf], b[nf], acc[mf][nf], 0, 0, 0);
    }
    __syncthreads();  // drains STAGE_A(kk+1); As[ab] reads done before reuse
    ab ^= 1;
  }
#undef STAGE_A

  if constexpr (EPI == 0) {
    short* out = (short*)outp;
#pragma unroll
    for (int mf = 0; mf < 4; ++mf)
#pragma unroll
      for (int r = 0; r < 4; ++r) {
        size_t off = ((size_t)n * kHW + sp0 + wm * 64 + mf * 16 + lhi * 4 + r) * kC
                     + co0 + wn * 64 + l15;
#pragma unroll
        for (int nf = 0; nf < 4; ++nf) out[off + nf * 16] = f2bf(acc[mf][nf][r]);
      }
  } else {
    float* out = (float*)outp;
    float* T = (float*)&As[0][0];  // 32 co x 128 sp, stride 129 (spans As[0..1], dead)
#pragma unroll 1
    for (int nf = 0; nf < 4; ++nf) {
      __syncthreads();
      const int coL = wn * 16 + l15;
#pragma unroll
      for (int mf = 0; mf < 4; ++mf)
#pragma unroll
        for (int r = 0; r < 4; ++r)
          T[coL * 129 + wm * 64 + mf * 16 + lhi * 4 + r] = acc[mf][nf][r];
      __syncthreads();
#pragma unroll
      for (int it = 0; it < 16; ++it) {
        int idx = it * 256 + tid;
        int c = idx >> 7, sp = idx & 127;
        int co = co0 + (c >> 4) * 64 + nf * 16 + (c & 15);
        size_t off = ((size_t)n * kC + co) * kHW + sp0 + sp;
        out[off] = T[c * 129 + sp] + xres[off];
      }
    }
  }
}

// ---- fused per-pixel attention (bf16 IO, fp32 LDS math) -------------------
__global__ __launch_bounds__(256) void attn_kernel(
    const short* q, const short* __restrict__ k,
    const short* __restrict__ v, short* virt) {
  __shared__ float Qs[32 * 66];
  __shared__ float Ks[32 * 66];
  __shared__ float Ps[32 * 36];
  const int p = blockIdx.x;
  const int tid = threadIdx.x;
  const int i  = tid >> 3;
  const int j0 = (tid & 7) * 4;
  float acc[4] = {0.f, 0.f, 0.f, 0.f};

  for (int c0 = 0; c0 < kC; c0 += 64) {
    __syncthreads();
    {
      int r = tid >> 3, c8 = (tid & 7) * 8;
      size_t g = ((size_t)r * kHW + p) * kC + c0 + c8;
      bf16x8 vq = *(const bf16x8*)&q[g];
      bf16x8 vk = *(const bf16x8*)&k[g];
#pragma unroll
      for (int jj = 0; jj < 8; ++jj) {
        Qs[r * 66 + c8 + jj] = bf2f(vq[jj]);
        Ks[r * 66 + c8 + jj] = bf2f(vk[jj]);
      }
    }
    __syncthreads();
#pragma unroll
    for (int c = 0; c < 64; ++c) {
      float qa = Qs[i * 66 + c];
      acc[0] = fmaf(qa, Ks[(j0 + 0) * 66 + c], acc[0]);
      acc[1] = fmaf(qa, Ks[(j0 + 1) * 66 + c], acc[1]);
      acc[2] = fmaf(qa, Ks[(j0 + 2) * 66 + c], acc[2]);
      acc[3] = fmaf(qa, Ks[(j0 + 3) * 66 + c], acc[3]);
    }
  }
  constexpr float scale = 0.044194173824159216f;  // 1/sqrt(512)
#pragma unroll
  for (int jj = 0; jj < 4; ++jj) acc[jj] *= scale;
  float m = fmaxf(fmaxf(acc[0], acc[1]), fmaxf(acc[2], acc[3]));
  for (int off = 1; off < 8; off <<= 1) m = fmaxf(m, __shfl_xor(m, off));
  float e[4];
  float s = 0.f;
#pragma unroll
  for (int jj = 0; jj < 4; ++jj) {
    e[jj] = __expf(acc[jj] - m);
    s += e[jj];
  }
  for (int off = 1; off < 8; off <<= 1) s += __shfl_xor(s, off);
  const float inv = 1.f / s;
#pragma unroll
  for (int jj = 0; jj < 4; ++jj) Ps[i * 36 + j0 + jj] = e[jj] * inv;

  const int c_ = tid & 63;
  const int i4 = tid >> 6;
  for (int c0 = 0; c0 < kC; c0 += 64) {
    __syncthreads();
    {
      int r = tid >> 3, c8 = (tid & 7) * 8;
      bf16x8 vv = *(const bf16x8*)&v[((size_t)r * kHW + p) * kC + c0 + c8];
#pragma unroll
      for (int jj = 0; jj < 8; ++jj) Qs[r * 66 + c8 + jj] = bf2f(vv[jj]);
    }
    __syncthreads();
#pragma unroll
    for (int it = 0; it < 8; ++it) {
      const int ii = i4 + it * 4;
      float o = 0.f;
#pragma unroll
      for (int j = 0; j < 32; ++j)
        o = fmaf(Ps[ii * 36 + j], Qs[j * 66 + c_], o);
      virt[((size_t)ii * kHW + p) * kC + c0 + c_] = f2bf(o);
    }
  }
}

// ---- GroupNorm(1,C) stats per instance ------------------------------------
__global__ __launch_bounds__(1024) void gn_stats_kernel(
    const short* __restrict__ virt, float* __restrict__ stats) {
  const int i = blockIdx.x;
  const short* src = virt + (size_t)i * kHW * kC;
  float s = 0.f, sq = 0.f;
  for (int idx = threadIdx.x; idx < kHW * kC / 8; idx += 1024) {
    bf16x8 vv = *(const bf16x8*)&src[(size_t)idx * 8];
#pragma unroll
    for (int jj = 0; jj < 8; ++jj) {
      float f = bf2f(vv[jj]);
      s += f;
      sq = fmaf(f, f, sq);
    }
  }
  __shared__ float rs[16], rq[16];
  for (int off = 1; off < 64; off <<= 1) {
    s += __shfl_xor(s, off);
    sq += __shfl_xor(sq, off);
  }
  const int lane = threadIdx.x & 63;
  const int wid = threadIdx.x >> 6;
  if (lane == 0) { rs[wid] = s; rq[wid] = sq; }
  __syncthreads();
  if (threadIdx.x < 16) {
    s = rs[threadIdx.x];
    sq = rq[threadIdx.x];
    for (int off = 1; off < 16; off <<= 1) {
      s += __shfl_xor(s, off);
      sq += __shfl_xor(sq, off);
    }
    if (threadIdx.x == 0) {
      constexpr float invn = 1.f / ((float)kHW * kC);
      float mean = s * invn;
      float var = sq * invn - mean * mean;
      stats[i] = mean;
      stats[32 + i] = rsqrtf(var + 1e-5f);
    }
  }
}

// ---- GN apply + affine + ReLU -> chunked-padded bf16 ----------------------
__global__ __launch_bounds__(256) void gn_apply_kernel(
    const short* __restrict__ virt, const float* __restrict__ stats,
    const float* __restrict__ gamma, const float* __restrict__ beta,
    short* __restrict__ vh) {
  const size_t g = (size_t)blockIdx.x * 256 + threadIdx.x;
  const int i    = (int)(g >> 16);
  const int rest = (int)(g & 65535);
  const int p    = rest >> 6;
  const int c8g  = rest & 63;
  const int ci   = c8g * 8;
  const float mean = stats[i];
  const float rstd = stats[32 + i];
  bf16x8 vv = *(const bf16x8*)&virt[((size_t)i * kHW + p) * kC + ci];
  const float4 ga = ((const float4*)gamma)[c8g * 2];
  const float4 gb = ((const float4*)gamma)[c8g * 2 + 1];
  const float4 ba = ((const float4*)beta)[c8g * 2];
  const float4 bb = ((const float4*)beta)[c8g * 2 + 1];
  const float gv[8] = {ga.x, ga.y, ga.z, ga.w, gb.x, gb.y, gb.z, gb.w};
  const float bv[8] = {ba.x, ba.y, ba.z, ba.w, bb.x, bb.y, bb.z, bb.w};
  bf16x8 o;
#pragma unroll
  for (int jj = 0; jj < 8; ++jj) {
    float f = (bf2f(vv[jj]) - mean) * rstd;
    f = fmaxf(fmaf(f, gv[jj], bv[jj]), 0.f);
    o[jj] = f2bf(f);
  }
  const size_t dst =
      (((size_t)i * 16 + (ci >> 5)) * 1156 + (size_t)((p >> 5) + 1) * 34 + (p & 31) + 1) * 32
      + (ci & 31);
  *(bf16x8*)&vh[dst] = o;
}

}  // namespace

extern "C" void kernel_launch(void* const* d_in, const int* in_sizes, int n_in,
                              void* d_out, int out_size, void* d_ws,
                              size_t ws_size, hipStream_t stream) {
  const float* x     = (const float*)d_in[0];
  const float* w_q   = (const float*)d_in[1];
  const float* w_k   = (const float*)d_in[2];
  const float* w_v   = (const float*)d_in[3];
  const float* w_o   = (const float*)d_in[4];
  const float* gamma = (const float*)d_in[5];
  const float* beta  = (const float*)d_in[6];

  short* ws    = (short*)d_ws;
  short* wtf_q = ws;
  short* wtf_k = wtf_q + WTF_ELEMS;
  short* wtf_v = wtf_k + WTF_ELEMS;
  short* wtf_o = wtf_v + WTF_ELEMS;
  short* xh    = wtf_o + WTF_ELEMS;
  short* vh    = xh + XH_ELEMS;
  short* qb    = vh + XH_ELEMS;
  short* kb    = qb + QKV_ELEMS;
  short* vb    = kb + QKV_ELEMS;
  float* stats = (float*)(vb + QKV_ELEMS);
  short* virt  = qb;  // attn writes per-position after reading q
  // zero halos of xh and vh (adjacent regions)
  hipMemsetAsync(xh, 0, (size_t)2 * XH_ELEMS * sizeof(short), stream);

  dim3 wg(16, 16);
  wtf_pack_kernel<<<wg, 256, 0, stream>>>(w_q, wtf_q);
  wtf_pack_kernel<<<wg, 256, 0, stream>>>(w_k, wtf_k);
  wtf_pack_kernel<<<wg, 256, 0, stream>>>(w_v, wtf_v);
  wtf_pack_kernel<<<wg, 256, 0, stream>>>(w_o, wtf_o);

  x2xh_kernel<<<dim3(16, 32, 32), 256, 0, stream>>>(x, xh);

  conv_mfma_kernel<0><<<1024, 256, 0, stream>>>(xh, wtf_q, nullptr, qb);
  conv_mfma_kernel<0><<<1024, 256, 0, stream>>>(xh, wtf_k, nullptr, kb);
  conv_mfma_kernel<0><<<1024, 256, 0, stream>>>(xh, wtf_v, nullptr, vb);

  attn_kernel<<<kHW, 256, 0, stream>>>(qb, kb, vb, virt);

  gn_stats_kernel<<<kN, 1024, 0, stream>>>(virt, stats);
  gn_apply_kernel<<<(int)(QKV_ELEMS / 8 / 256), 256, 0, stream>>>(
      virt, stats, gamma, beta, vh);

  conv_mfma_kernel<1><<<1024, 256, 0, stream>>>(vh, wtf_o, x, (void*)d_out);
}

// Round 5
// 784.667 us; speedup vs baseline: 10.7020x; 1.1914x over previous
//
#include <hip/hip_runtime.h>

namespace {

constexpr int kN  = 32;
constexpr int kC  = 512;
constexpr int kH  = 32;
constexpr int kW  = 32;
constexpr int kHW = kH * kW;

// bf16 chunked-padded activation layout: [n][chunk=ci/32][34 rows][34 cols][32 ci]
constexpr int PCH   = 36992;                 // 34*34*32 elems per (n,chunk) plane
constexpr size_t WTF_ELEMS = (size_t)9 * kC * kC;          // 2,359,296 bf16
constexpr size_t XH_ELEMS  = (size_t)kN * 16 * PCH;        // 18,939,904 bf16
constexpr size_t QKV_ELEMS = (size_t)kN * kHW * kC;        // 16,777,216 bf16

using bf16x8 = __attribute__((ext_vector_type(8))) short;
using bf16x4 = __attribute__((ext_vector_type(4))) short;
using f32x4  = __attribute__((ext_vector_type(4))) float;

__device__ __forceinline__ float bf2f(short s) {
  unsigned u = ((unsigned)(unsigned short)s) << 16;
  return __builtin_bit_cast(float, u);
}
__device__ __forceinline__ short f2bf(float f) {
  unsigned u = __builtin_bit_cast(unsigned, f);
  u += 0x7FFFu + ((u >> 16) & 1u);
  return (short)(u >> 16);
}
__device__ __forceinline__ void gload_lds16(const void* g, void* l) {
  __builtin_amdgcn_global_load_lds(
      (const __attribute__((address_space(1))) void*)g,
      (__attribute__((address_space(3))) void*)l, 16, 0, 0);
}

// ---- weight pack: w[co][ci][3][3] f32 -> wtf[t][kk][nnG][lane][8] bf16 ----
// lane = (co&15) | (hi<<4), j = ci&7, hi = (ci>>3)&3, kk = ci>>5, nnG = co>>4
__global__ __launch_bounds__(256) void wtf_pack_kernel(
    const float* __restrict__ w, short* __restrict__ wtf) {
  __shared__ float tile[32][289];  // [co][ci*9+t]
  const int co0 = blockIdx.x * 32;
  const int ci0 = blockIdx.y * 32;
  for (int idx = threadIdx.x; idx < 32 * 288; idx += 256) {
    int c = idx % 288, r = idx / 288;
    tile[r][c] = w[(size_t)(co0 + r) * (kC * 9) + (size_t)ci0 * 9 + c];
  }
  __syncthreads();
  const int kkb  = ci0 >> 5;
  const int nnG0 = co0 >> 4;
  for (int g = threadIdx.x; g < 9 * 2 * 64; g += 256) {
    int laneg = g & 63;
    int nnL   = (g >> 6) & 1;
    int t     = g >> 7;  // 0..8
    int hi    = laneg >> 4;
    int coL   = nnL * 16 + (laneg & 15);
    bf16x8 pk;
#pragma unroll
    for (int j = 0; j < 8; ++j) pk[j] = f2bf(tile[coL][(hi * 8 + j) * 9 + t]);
    *(bf16x8*)&wtf[(((size_t)t * 16 + kkb) * 32 + nnG0 + nnL) * 512 + laneg * 8] = pk;
  }
}

// ---- x NCHW f32 -> xh chunked-padded bf16 ---------------------------------
__global__ __launch_bounds__(256) void x2xh_kernel(
    const float* __restrict__ x, short* __restrict__ xh) {
  __shared__ float tile[32][33];  // [w][ci]
  const int ch = blockIdx.x;   // 0..15
  const int h  = blockIdx.y;   // 0..31
  const int n  = blockIdx.z;   // 0..31
  const int w0 = threadIdx.x & 31;
  const int c0 = threadIdx.x >> 5;  // 8 ci rows per pass
#pragma unroll
  for (int pass = 0; pass < 4; ++pass) {
    int cir = pass * 8 + c0;
    tile[w0][cir] = x[(((size_t)n * kC + ch * 32 + cir) * kH + h) * kW + w0];
  }
  __syncthreads();
  // wv in 0..31, g4 in {0,4,...,28}: exactly covers ci 0..31, no OOB.
  const int wv = threadIdx.x >> 3;
  const int g4 = (threadIdx.x & 7) * 4;
  bf16x4 pk;
#pragma unroll
  for (int j = 0; j < 4; ++j) pk[j] = f2bf(tile[wv][g4 + j]);
  *(bf16x4*)&xh[(((size_t)n * 16 + ch) * 1156 + (size_t)(h + 1) * 34 + (wv + 1)) * 32 + g4] = pk;
}

// ---- conv3x3 via MFMA implicit shift-GEMM ---------------------------------
// A: triple-buffered LDS staging, counted vmcnt across raw s_barrier (T3/T4):
//   iter kk: s_waitcnt vmcnt(4)  (stage kk landed; stage kk+1 stays in flight)
//            s_barrier
//            STAGE(kk+2)         (issue next-next; 8 outstanding max)
//            144 MFMAs on buf kk
// B (weights) loaded straight from global (fragment-linear wtf, L2-hot).
// EPI 0: out = bf16 NHWC [n][sp][co]
// EPI 1: out = f32 NCHW + residual xres (f32 NCHW)
template <int EPI>
__global__ __launch_bounds__(256, 3) void conv_mfma_kernel(
    const short* __restrict__ xin, const short* __restrict__ wtf,
    const float* __restrict__ xres, void* __restrict__ outp) {
  __shared__ __align__(16) short As[3][8192];  // [pos 256][ci 32] bf16, x3
  const int tid  = threadIdx.x;
  const int lane = tid & 63;
  const int l15  = lane & 15, lhi = lane >> 4;
  const int wv   = tid >> 6;
  const int wm   = wv >> 1, wn = wv & 1;
  const int wbase = tid & 192;

  // XCD-chunked swizzle: 1024 blocks, 8 XCDs, 128/XCD = 4 full images.
  const int swz = ((blockIdx.x & 7) << 7) | (blockIdx.x >> 3);
  const int co0 = (swz & 3) * 128;
  const int spt = (swz >> 2) & 7;
  const int h0  = spt * 4;
  const int sp0 = spt * 128;
  const int n   = swz >> 5;

  const short* srcA = xin + (size_t)n * (16 * PCH) + (size_t)h0 * (34 * 32);
  // per-thread B pointer: frag-linear [t*16+kk][nnG][lane*8]
  const short* bptr = wtf + ((size_t)(co0 >> 4) + wn * 4) * 512 + lane * 8;

  f32x4 acc[4][4];
#pragma unroll
  for (int mf = 0; mf < 4; ++mf)
#pragma unroll
    for (int nf = 0; nf < 4; ++nf)
#pragma unroll
      for (int r = 0; r < 4; ++r) acc[mf][nf][r] = 0.f;

  // Linear stage: LDS mirrors the global 204*64B slab byte-for-byte.
  // (tail over-reads <3.3KB land in the adjacent allocated ws buffer; the
  //  corresponding LDS positions 204..255 are never read.)
#define STAGE_A(kk, buf)                                                      \
  {                                                                           \
    const short* gA = srcA + (size_t)(kk) * PCH;                              \
    _Pragma("unroll") for (int pass = 0; pass < 4; ++pass)                    \
        gload_lds16(gA + (size_t)(pass * 256 + tid) * 8,                      \
                    &As[buf][(pass * 256 + wbase) * 8]);                      \
  }

  STAGE_A(0, 0);
  STAGE_A(1, 1);
  int ab = 0;   // buffer holding stage kk
  int sb = 2;   // buffer to stage kk+2 into
  for (int kk = 0; kk < 16; ++kk) {
    // stage kk's 4 loads (per wave) are everything except the newest 4
    // (stage kk+1). Wait BEFORE the barrier: each wave certifies its own
    // contribution, the barrier makes it global.
    asm volatile("s_waitcnt vmcnt(4)" ::: "memory");
    __builtin_amdgcn_s_barrier();
    if (kk < 14) STAGE_A(kk + 2, sb);
#pragma unroll
    for (int t = 0; t < 9; ++t) {
      const int dy = t / 3, dx = t % 3;  // compile-time (t unrolled)
      const short* bt = bptr + (size_t)(t * 16 + kk) * 16384;
      bf16x8 a[4], b[4];
#pragma unroll
      for (int nf = 0; nf < 4; ++nf)
        b[nf] = *(const bf16x8*)&bt[nf * 512];
#pragma unroll
      for (int mf = 0; mf < 4; ++mf) {
        const int pb = (wm * 2 + (mf >> 1) + dy) * 34 + (mf & 1) * 16 + l15 + dx;
        a[mf] = *(const bf16x8*)&As[ab][pb * 32 + lhi * 8];
      }
#pragma unroll
      for (int mf = 0; mf < 4; ++mf)
#pragma unroll
        for (int nf = 0; nf < 4; ++nf)
          acc[mf][nf] = __builtin_amdgcn_mfma_f32_16x16x32_bf16(
              a[mf], b[nf], acc[mf][nf], 0, 0, 0);
    }
    ab = (ab == 2) ? 0 : ab + 1;
    sb = (sb == 2) ? 0 : sb + 1;
  }
#undef STAGE_A

  if constexpr (EPI == 0) {
    short* out = (short*)outp;
#pragma unroll
    for (int mf = 0; mf < 4; ++mf)
#pragma unroll
      for (int r = 0; r < 4; ++r) {
        size_t off = ((size_t)n * kHW + sp0 + wm * 64 + mf * 16 + lhi * 4 + r) * kC
                     + co0 + wn * 64 + l15;
#pragma unroll
        for (int nf = 0; nf < 4; ++nf) out[off + nf * 16] = f2bf(acc[mf][nf][r]);
      }
  } else {
    float* out = (float*)outp;
    float* T = (float*)&As[0][0];  // 32 co x 128 sp, stride 129 (16.5 KB, dead)
#pragma unroll 1
    for (int nf = 0; nf < 4; ++nf) {
      __syncthreads();
      const int coL = wn * 16 + l15;
#pragma unroll
      for (int mf = 0; mf < 4; ++mf)
#pragma unroll
        for (int r = 0; r < 4; ++r)
          T[coL * 129 + wm * 64 + mf * 16 + lhi * 4 + r] = acc[mf][nf][r];
      __syncthreads();
#pragma unroll
      for (int it = 0; it < 16; ++it) {
        int idx = it * 256 + tid;
        int c = idx >> 7, sp = idx & 127;
        int co = co0 + (c >> 4) * 64 + nf * 16 + (c & 15);
        size_t off = ((size_t)n * kC + co) * kHW + sp0 + sp;
        out[off] = T[c * 129 + sp] + xres[off];
      }
    }
  }
}

// ---- fused per-pixel attention (bf16 IO, fp32 LDS math) -------------------
__global__ __launch_bounds__(256) void attn_kernel(
    const short* q, const short* __restrict__ k,
    const short* __restrict__ v, short* virt) {
  __shared__ float Qs[32 * 66];
  __shared__ float Ks[32 * 66];
  __shared__ float Ps[32 * 36];
  const int p = blockIdx.x;
  const int tid = threadIdx.x;
  const int i  = tid >> 3;
  const int j0 = (tid & 7) * 4;
  float acc[4] = {0.f, 0.f, 0.f, 0.f};

  for (int c0 = 0; c0 < kC; c0 += 64) {
    __syncthreads();
    {
      int r = tid >> 3, c8 = (tid & 7) * 8;
      size_t g = ((size_t)r * kHW + p) * kC + c0 + c8;
      bf16x8 vq = *(const bf16x8*)&q[g];
      bf16x8 vk = *(const bf16x8*)&k[g];
#pragma unroll
      for (int jj = 0; jj < 8; ++jj) {
        Qs[r * 66 + c8 + jj] = bf2f(vq[jj]);
        Ks[r * 66 + c8 + jj] = bf2f(vk[jj]);
      }
    }
    __syncthreads();
#pragma unroll
    for (int c = 0; c < 64; ++c) {
      float qa = Qs[i * 66 + c];
      acc[0] = fmaf(qa, Ks[(j0 + 0) * 66 + c], acc[0]);
      acc[1] = fmaf(qa, Ks[(j0 + 1) * 66 + c], acc[1]);
      acc[2] = fmaf(qa, Ks[(j0 + 2) * 66 + c], acc[2]);
      acc[3] = fmaf(qa, Ks[(j0 + 3) * 66 + c], acc[3]);
    }
  }
  constexpr float scale = 0.044194173824159216f;  // 1/sqrt(512)
#pragma unroll
  for (int jj = 0; jj < 4; ++jj) acc[jj] *= scale;
  float m = fmaxf(fmaxf(acc[0], acc[1]), fmaxf(acc[2], acc[3]));
  for (int off = 1; off < 8; off <<= 1) m = fmaxf(m, __shfl_xor(m, off));
  float e[4];
  float s = 0.f;
#pragma unroll
  for (int jj = 0; jj < 4; ++jj) {
    e[jj] = __expf(acc[jj] - m);
    s += e[jj];
  }
  for (int off = 1; off < 8; off <<= 1) s += __shfl_xor(s, off);
  const float inv = 1.f / s;
#pragma unroll
  for (int jj = 0; jj < 4; ++jj) Ps[i * 36 + j0 + jj] = e[jj] * inv;

  const int c_ = tid & 63;
  const int i4 = tid >> 6;
  for (int c0 = 0; c0 < kC; c0 += 64) {
    __syncthreads();
    {
      int r = tid >> 3, c8 = (tid & 7) * 8;
      bf16x8 vv = *(const bf16x8*)&v[((size_t)r * kHW + p) * kC + c0 + c8];
#pragma unroll
      for (int jj = 0; jj < 8; ++jj) Qs[r * 66 + c8 + jj] = bf2f(vv[jj]);
    }
    __syncthreads();
#pragma unroll
    for (int it = 0; it < 8; ++it) {
      const int ii = i4 + it * 4;
      float o = 0.f;
#pragma unroll
      for (int j = 0; j < 32; ++j)
        o = fmaf(Ps[ii * 36 + j], Qs[j * 66 + c_], o);
      virt[((size_t)ii * kHW + p) * kC + c0 + c_] = f2bf(o);
    }
  }
}

// ---- GroupNorm(1,C) stats per instance ------------------------------------
__global__ __launch_bounds__(1024) void gn_stats_kernel(
    const short* __restrict__ virt, float* __restrict__ stats) {
  const int i = blockIdx.x;
  const short* src = virt + (size_t)i * kHW * kC;
  float s = 0.f, sq = 0.f;
  for (int idx = threadIdx.x; idx < kHW * kC / 8; idx += 1024) {
    bf16x8 vv = *(const bf16x8*)&src[(size_t)idx * 8];
#pragma unroll
    for (int jj = 0; jj < 8; ++jj) {
      float f = bf2f(vv[jj]);
      s += f;
      sq = fmaf(f, f, sq);
    }
  }
  __shared__ float rs[16], rq[16];
  for (int off = 1; off < 64; off <<= 1) {
    s += __shfl_xor(s, off);
    sq += __shfl_xor(sq, off);
  }
  const int lane = threadIdx.x & 63;
  const int wid = threadIdx.x >> 6;
  if (lane == 0) { rs[wid] = s; rq[wid] = sq; }
  __syncthreads();
  if (threadIdx.x < 16) {
    s = rs[threadIdx.x];
    sq = rq[threadIdx.x];
    for (int off = 1; off < 16; off <<= 1) {
      s += __shfl_xor(s, off);
      sq += __shfl_xor(sq, off);
    }
    if (threadIdx.x == 0) {
      constexpr float invn = 1.f / ((float)kHW * kC);
      float mean = s * invn;
      float var = sq * invn - mean * mean;
      stats[i] = mean;
      stats[32 + i] = rsqrtf(var + 1e-5f);
    }
  }
}

// ---- GN apply + affine + ReLU -> chunked-padded bf16 ----------------------
__global__ __launch_bounds__(256) void gn_apply_kernel(
    const short* __restrict__ virt, const float* __restrict__ stats,
    const float* __restrict__ gamma, const float* __restrict__ beta,
    short* __restrict__ vh) {
  const size_t g = (size_t)blockIdx.x * 256 + threadIdx.x;
  const int i    = (int)(g >> 16);
  const int rest = (int)(g & 65535);
  const int p    = rest >> 6;
  const int c8g  = rest & 63;
  const int ci   = c8g * 8;
  const float mean = stats[i];
  const float rstd = stats[32 + i];
  bf16x8 vv = *(const bf16x8*)&virt[((size_t)i * kHW + p) * kC + ci];
  const float4 ga = ((const float4*)gamma)[c8g * 2];
  const float4 gb = ((const float4*)gamma)[c8g * 2 + 1];
  const float4 ba = ((const float4*)beta)[c8g * 2];
  const float4 bb = ((const float4*)beta)[c8g * 2 + 1];
  const float gv[8] = {ga.x, ga.y, ga.z, ga.w, gb.x, gb.y, gb.z, gb.w};
  const float bv[8] = {ba.x, ba.y, ba.z, ba.w, bb.x, bb.y, bb.z, bb.w};
  bf16x8 o;
#pragma unroll
  for (int jj = 0; jj < 8; ++jj) {
    float f = (bf2f(vv[jj]) - mean) * rstd;
    f = fmaxf(fmaf(f, gv[jj], bv[jj]), 0.f);
    o[jj] = f2bf(f);
  }
  const size_t dst =
      (((size_t)i * 16 + (ci >> 5)) * 1156 + (size_t)((p >> 5) + 1) * 34 + (p & 31) + 1) * 32
      + (ci & 31);
  *(bf16x8*)&vh[dst] = o;
}

}  // namespace

extern "C" void kernel_launch(void* const* d_in, const int* in_sizes, int n_in,
                              void* d_out, int out_size, void* d_ws,
                              size_t ws_size, hipStream_t stream) {
  const float* x     = (const float*)d_in[0];
  const float* w_q   = (const float*)d_in[1];
  const float* w_k   = (const float*)d_in[2];
  const float* w_v   = (const float*)d_in[3];
  const float* w_o   = (const float*)d_in[4];
  const float* gamma = (const float*)d_in[5];
  const float* beta  = (const float*)d_in[6];

  short* ws    = (short*)d_ws;
  short* wtf_q = ws;
  short* wtf_k = wtf_q + WTF_ELEMS;
  short* wtf_v = wtf_k + WTF_ELEMS;
  short* wtf_o = wtf_v + WTF_ELEMS;
  short* xh    = wtf_o + WTF_ELEMS;
  short* vh    = xh + XH_ELEMS;
  short* qb    = vh + XH_ELEMS;
  short* kb    = qb + QKV_ELEMS;
  short* vb    = kb + QKV_ELEMS;
  float* stats = (float*)(vb + QKV_ELEMS);
  short* virt  = qb;  // attn writes per-position after reading q
  // zero halos of xh and vh (adjacent regions)
  hipMemsetAsync(xh, 0, (size_t)2 * XH_ELEMS * sizeof(short), stream);

  dim3 wg(16, 16);
  wtf_pack_kernel<<<wg, 256, 0, stream>>>(w_q, wtf_q);
  wtf_pack_kernel<<<wg, 256, 0, stream>>>(w_k, wtf_k);
  wtf_pack_kernel<<<wg, 256, 0, stream>>>(w_v, wtf_v);
  wtf_pack_kernel<<<wg, 256, 0, stream>>>(w_o, wtf_o);

  x2xh_kernel<<<dim3(16, 32, 32), 256, 0, stream>>>(x, xh);

  conv_mfma_kernel<0><<<1024, 256, 0, stream>>>(xh, wtf_q, nullptr, qb);
  conv_mfma_kernel<0><<<1024, 256, 0, stream>>>(xh, wtf_k, nullptr, kb);
  conv_mfma_kernel<0><<<1024, 256, 0, stream>>>(xh, wtf_v, nullptr, vb);

  attn_kernel<<<kHW, 256, 0, stream>>>(qb, kb, vb, virt);

  gn_stats_kernel<<<kN, 1024, 0, stream>>>(virt, stats);
  gn_apply_kernel<<<(int)(QKV_ELEMS / 8 / 256), 256, 0, stream>>>(
      virt, stats, gamma, beta, vh);

  conv_mfma_kernel<1><<<1024, 256, 0, stream>>>(vh, wtf_o, x, (void*)d_out);
}

// Round 6
// 704.076 us; speedup vs baseline: 11.9270x; 1.1145x over previous
//
#include <hip/hip_runtime.h>

namespace {

constexpr int kN  = 32;
constexpr int kC  = 512;
constexpr int kH  = 32;
constexpr int kW  = 32;
constexpr int kHW = kH * kW;

// bf16 chunked-padded activation layout: [n][chunk=ci/32][34 rows][34 cols][32 ci]
constexpr int PCH   = 36992;                 // 34*34*32 elems per (n,chunk) plane
constexpr size_t WTF_ELEMS = (size_t)9 * kC * kC;          // 2,359,296 bf16
constexpr size_t XH_ELEMS  = (size_t)kN * 16 * PCH;        // 18,939,904 bf16
constexpr size_t QKV_ELEMS = (size_t)kN * kHW * kC;        // 16,777,216 bf16

using bf16x8 = __attribute__((ext_vector_type(8))) short;
using bf16x4 = __attribute__((ext_vector_type(4))) short;
using f32x4  = __attribute__((ext_vector_type(4))) float;

__device__ __forceinline__ float bf2f(short s) {
  unsigned u = ((unsigned)(unsigned short)s) << 16;
  return __builtin_bit_cast(float, u);
}
__device__ __forceinline__ short f2bf(float f) {
  unsigned u = __builtin_bit_cast(unsigned, f);
  u += 0x7FFFu + ((u >> 16) & 1u);
  return (short)(u >> 16);
}
__device__ __forceinline__ void gload_lds16(const void* g, void* l) {
  __builtin_amdgcn_global_load_lds(
      (const __attribute__((address_space(1))) void*)g,
      (__attribute__((address_space(3))) void*)l, 16, 0, 0);
}

// ---- weight pack: w[co][ci][3][3] f32 -> wtf[t][kk][nnG][lane][8] bf16 ----
__global__ __launch_bounds__(256) void wtf_pack_kernel(
    const float* __restrict__ w, short* __restrict__ wtf) {
  __shared__ float tile[32][289];  // [co][ci*9+t]
  const int co0 = blockIdx.x * 32;
  const int ci0 = blockIdx.y * 32;
  for (int idx = threadIdx.x; idx < 32 * 288; idx += 256) {
    int c = idx % 288, r = idx / 288;
    tile[r][c] = w[(size_t)(co0 + r) * (kC * 9) + (size_t)ci0 * 9 + c];
  }
  __syncthreads();
  const int kkb  = ci0 >> 5;
  const int nnG0 = co0 >> 4;
  for (int g = threadIdx.x; g < 9 * 2 * 64; g += 256) {
    int laneg = g & 63;
    int nnL   = (g >> 6) & 1;
    int t     = g >> 7;  // 0..8
    int hi    = laneg >> 4;
    int coL   = nnL * 16 + (laneg & 15);
    bf16x8 pk;
#pragma unroll
    for (int j = 0; j < 8; ++j) pk[j] = f2bf(tile[coL][(hi * 8 + j) * 9 + t]);
    *(bf16x8*)&wtf[(((size_t)t * 16 + kkb) * 32 + nnG0 + nnL) * 512 + laneg * 8] = pk;
  }
}

// ---- x NCHW f32 -> xh chunked-padded bf16 ---------------------------------
__global__ __launch_bounds__(256) void x2xh_kernel(
    const float* __restrict__ x, short* __restrict__ xh) {
  __shared__ float tile[32][33];  // [w][ci]
  const int ch = blockIdx.x;   // 0..15
  const int h  = blockIdx.y;   // 0..31
  const int n  = blockIdx.z;   // 0..31
  const int w0 = threadIdx.x & 31;
  const int c0 = threadIdx.x >> 5;
#pragma unroll
  for (int pass = 0; pass < 4; ++pass) {
    int cir = pass * 8 + c0;
    tile[w0][cir] = x[(((size_t)n * kC + ch * 32 + cir) * kH + h) * kW + w0];
  }
  __syncthreads();
  const int wv = threadIdx.x >> 3;
  const int g4 = (threadIdx.x & 7) * 4;
  bf16x4 pk;
#pragma unroll
  for (int j = 0; j < 4; ++j) pk[j] = f2bf(tile[wv][g4 + j]);
  *(bf16x4*)&xh[(((size_t)n * 16 + ch) * 1156 + (size_t)(h + 1) * 34 + (wv + 1)) * 32 + g4] = pk;
}

// ---- FUSED q/k/v conv3x3 via MFMA implicit shift-GEMM ---------------------
// Tile: sp 128 x co 64, 3 output tensors. A staged to LDS (triple buffer,
// counted vmcnt across raw barrier); B prefetched 1 tap ahead in registers,
// STAGE issued at t==1 so B-waits never drain it (vmcnt FIFO, oldest-first).
__global__ __launch_bounds__(256, 2) void conv_qkv_kernel(
    const short* __restrict__ xin,
    const short* __restrict__ wtq, const short* __restrict__ wtk,
    const short* __restrict__ wtv,
    short* __restrict__ outq, short* __restrict__ outk,
    short* __restrict__ outv) {
  __shared__ __align__(16) short As[3][8192];  // [pos 256][ci 32] bf16, x3
  const int tid  = threadIdx.x;
  const int lane = tid & 63;
  const int l15  = lane & 15, lhi = lane >> 4;
  const int wv   = tid >> 6;
  const int wm   = wv >> 1, wn = wv & 1;
  const int wbase = tid & 192;

  // 2048 blocks, 8 XCDs -> 256/XCD: co fastest (8 co-blocks share an A-slab
  // within one XCD's L2), then spt, then n (4 images per XCD).
  const int swz = ((blockIdx.x & 7) << 8) | (blockIdx.x >> 3);
  const int co0 = (swz & 7) * 64;
  const int spt = (swz >> 3) & 7;
  const int h0  = spt * 4;
  const int sp0 = spt * 128;
  const int n   = swz >> 6;

  const short* srcA = xin + (size_t)n * (16 * PCH) + (size_t)h0 * (34 * 32);
  const size_t boff = ((size_t)(co0 >> 4) + wn * 2) * 512 + lane * 8;
  const short* bp[3] = {wtq + boff, wtk + boff, wtv + boff};

  f32x4 acc[3][4][2];
#pragma unroll
  for (int c = 0; c < 3; ++c)
#pragma unroll
    for (int mf = 0; mf < 4; ++mf)
#pragma unroll
      for (int nf = 0; nf < 2; ++nf)
#pragma unroll
        for (int r = 0; r < 4; ++r) acc[c][mf][nf][r] = 0.f;

#define STAGE_A(kk, buf)                                                      \
  {                                                                           \
    const short* gA = srcA + (size_t)(kk) * PCH;                              \
    _Pragma("unroll") for (int pass = 0; pass < 4; ++pass)                    \
        gload_lds16(gA + (size_t)(pass * 256 + tid) * 8,                      \
                    &As[buf][(pass * 256 + wbase) * 8]);                      \
  }

  STAGE_A(0, 0);
  STAGE_A(1, 1);
  bf16x8 cur[6], nxt[6];
#pragma unroll
  for (int j = 0; j < 6; ++j)  // b(kk=0, t=0): issued AFTER the two stages
    cur[j] = *(const bf16x8*)&bp[j >> 1][(size_t)(j & 1) * 512];

  int ab = 0;   // buffer holding stage kk
  int sb = 2;   // buffer to stage kk+2 into
  for (int kk = 0; kk < 16; ++kk) {
    // Younger-than-stage(kk) queue entries possibly in flight here:
    // stage(kk+1) 4 + prefetched b(kk,0) 6 = 10. stage(kk) is >=96 issues
    // deep -> vmcnt(10) certifies it retired without draining prefetches.
    asm volatile("s_waitcnt vmcnt(10)" ::: "memory");
    __builtin_amdgcn_s_barrier();
#pragma unroll
    for (int t = 0; t < 9; ++t) {
      {  // prefetch next tap's B (t==8: next kk's tap 0; harmless pad at end)
        const int nt  = (t < 8) ? (t + 1) : 0;
        const int nkk = (t < 8) ? kk : kk + 1;
        const size_t bo = (size_t)(nt * 16 + nkk) * 16384;
#pragma unroll
        for (int j = 0; j < 6; ++j)
          nxt[j] = *(const bf16x8*)&bp[j >> 1][bo + (size_t)(j & 1) * 512];
      }
      if (t == 1 && kk < 14) STAGE_A(kk + 2, sb);
      const int dy = t / 3, dx = t % 3;
      bf16x8 a[4];
#pragma unroll
      for (int mf = 0; mf < 4; ++mf) {
        const int pb = (wm * 2 + (mf >> 1) + dy) * 34 + (mf & 1) * 16 + l15 + dx;
        a[mf] = *(const bf16x8*)&As[ab][pb * 32 + lhi * 8];
      }
      __builtin_amdgcn_s_setprio(1);
#pragma unroll
      for (int c = 0; c < 3; ++c)
#pragma unroll
        for (int mf = 0; mf < 4; ++mf)
#pragma unroll
          for (int nf = 0; nf < 2; ++nf)
            acc[c][mf][nf] = __builtin_amdgcn_mfma_f32_16x16x32_bf16(
                a[mf], cur[c * 2 + nf], acc[c][mf][nf], 0, 0, 0);
      __builtin_amdgcn_s_setprio(0);
#pragma unroll
      for (int j = 0; j < 6; ++j) cur[j] = nxt[j];
    }
    ab = (ab == 2) ? 0 : ab + 1;
    sb = (sb == 2) ? 0 : sb + 1;
  }
#undef STAGE_A

  short* outs[3] = {outq, outk, outv};
#pragma unroll
  for (int c = 0; c < 3; ++c) {
    short* out = outs[c];
#pragma unroll
    for (int mf = 0; mf < 4; ++mf)
#pragma unroll
      for (int r = 0; r < 4; ++r) {
        size_t off = ((size_t)n * kHW + sp0 + wm * 64 + mf * 16 + lhi * 4 + r) * kC
                     + co0 + wn * 32 + l15;
#pragma unroll
        for (int nf = 0; nf < 2; ++nf) out[off + nf * 16] = f2bf(acc[c][mf][nf][r]);
      }
  }
}

// ---- conv_o (single conv, 128x128 tile) with the same prefetch skeleton ---
// EPI: f32 NCHW output + residual add.
__global__ __launch_bounds__(256, 3) void conv_o_kernel(
    const short* __restrict__ xin, const short* __restrict__ wtf,
    const float* __restrict__ xres, float* __restrict__ out) {
  __shared__ __align__(16) short As[3][8192];
  const int tid  = threadIdx.x;
  const int lane = tid & 63;
  const int l15  = lane & 15, lhi = lane >> 4;
  const int wv   = tid >> 6;
  const int wm   = wv >> 1, wn = wv & 1;
  const int wbase = tid & 192;

  const int swz = ((blockIdx.x & 7) << 7) | (blockIdx.x >> 3);
  const int co0 = (swz & 3) * 128;
  const int spt = (swz >> 2) & 7;
  const int h0  = spt * 4;
  const int sp0 = spt * 128;
  const int n   = swz >> 5;

  const short* srcA = xin + (size_t)n * (16 * PCH) + (size_t)h0 * (34 * 32);
  const short* bptr = wtf + ((size_t)(co0 >> 4) + wn * 4) * 512 + lane * 8;

  f32x4 acc[4][4];
#pragma unroll
  for (int mf = 0; mf < 4; ++mf)
#pragma unroll
    for (int nf = 0; nf < 4; ++nf)
#pragma unroll
      for (int r = 0; r < 4; ++r) acc[mf][nf][r] = 0.f;

#define STAGE_A(kk, buf)                                                      \
  {                                                                           \
    const short* gA = srcA + (size_t)(kk) * PCH;                              \
    _Pragma("unroll") for (int pass = 0; pass < 4; ++pass)                    \
        gload_lds16(gA + (size_t)(pass * 256 + tid) * 8,                      \
                    &As[buf][(pass * 256 + wbase) * 8]);                      \
  }

  STAGE_A(0, 0);
  STAGE_A(1, 1);
  bf16x8 cur[4], nxt[4];
#pragma unroll
  for (int j = 0; j < 4; ++j)
    cur[j] = *(const bf16x8*)&bptr[(size_t)j * 512];

  int ab = 0, sb = 2;
  for (int kk = 0; kk < 16; ++kk) {
    asm volatile("s_waitcnt vmcnt(8)" ::: "memory");
    __builtin_amdgcn_s_barrier();
#pragma unroll
    for (int t = 0; t < 9; ++t) {
      {
        const int nt  = (t < 8) ? (t + 1) : 0;
        const int nkk = (t < 8) ? kk : kk + 1;
        const size_t bo = (size_t)(nt * 16 + nkk) * 16384;
#pragma unroll
        for (int j = 0; j < 4; ++j)
          nxt[j] = *(const bf16x8*)&bptr[bo + (size_t)j * 512];
      }
      if (t == 1 && kk < 14) STAGE_A(kk + 2, sb);
      const int dy = t / 3, dx = t % 3;
      bf16x8 a[4];
#pragma unroll
      for (int mf = 0; mf < 4; ++mf) {
        const int pb = (wm * 2 + (mf >> 1) + dy) * 34 + (mf & 1) * 16 + l15 + dx;
        a[mf] = *(const bf16x8*)&As[ab][pb * 32 + lhi * 8];
      }
      __builtin_amdgcn_s_setprio(1);
#pragma unroll
      for (int mf = 0; mf < 4; ++mf)
#pragma unroll
        for (int nf = 0; nf < 4; ++nf)
          acc[mf][nf] = __builtin_amdgcn_mfma_f32_16x16x32_bf16(
              a[mf], cur[nf], acc[mf][nf], 0, 0, 0);
      __builtin_amdgcn_s_setprio(0);
#pragma unroll
      for (int j = 0; j < 4; ++j) cur[j] = nxt[j];
    }
    ab = (ab == 2) ? 0 : ab + 1;
    sb = (sb == 2) ? 0 : sb + 1;
  }
#undef STAGE_A

  float* T = (float*)&As[0][0];  // 32 co x 128 sp, stride 129 (LDS dead now)
#pragma unroll 1
  for (int nf = 0; nf < 4; ++nf) {
    __syncthreads();
    const int coL = wn * 16 + l15;
#pragma unroll
    for (int mf = 0; mf < 4; ++mf)
#pragma unroll
      for (int r = 0; r < 4; ++r)
        T[coL * 129 + wm * 64 + mf * 16 + lhi * 4 + r] = acc[mf][nf][r];
    __syncthreads();
#pragma unroll
    for (int it = 0; it < 16; ++it) {
      int idx = it * 256 + tid;
      int c = idx >> 7, sp = idx & 127;
      int co = co0 + (c >> 4) * 64 + nf * 16 + (c & 15);
      size_t off = ((size_t)n * kC + co) * kHW + sp0 + sp;
      out[off] = T[c * 129 + sp] + xres[off];
    }
  }
}

// ---- fused per-pixel attention (bf16 IO, fp32 LDS math) -------------------
__global__ __launch_bounds__(256) void attn_kernel(
    const short* q, const short* __restrict__ k,
    const short* __restrict__ v, short* virt) {
  __shared__ float Qs[32 * 66];
  __shared__ float Ks[32 * 66];
  __shared__ float Ps[32 * 36];
  const int p = blockIdx.x;
  const int tid = threadIdx.x;
  const int i  = tid >> 3;
  const int j0 = (tid & 7) * 4;
  float acc[4] = {0.f, 0.f, 0.f, 0.f};

  for (int c0 = 0; c0 < kC; c0 += 64) {
    __syncthreads();
    {
      int r = tid >> 3, c8 = (tid & 7) * 8;
      size_t g = ((size_t)r * kHW + p) * kC + c0 + c8;
      bf16x8 vq = *(const bf16x8*)&q[g];
      bf16x8 vk = *(const bf16x8*)&k[g];
#pragma unroll
      for (int jj = 0; jj < 8; ++jj) {
        Qs[r * 66 + c8 + jj] = bf2f(vq[jj]);
        Ks[r * 66 + c8 + jj] = bf2f(vk[jj]);
      }
    }
    __syncthreads();
#pragma unroll
    for (int c = 0; c < 64; ++c) {
      float qa = Qs[i * 66 + c];
      acc[0] = fmaf(qa, Ks[(j0 + 0) * 66 + c], acc[0]);
      acc[1] = fmaf(qa, Ks[(j0 + 1) * 66 + c], acc[1]);
      acc[2] = fmaf(qa, Ks[(j0 + 2) * 66 + c], acc[2]);
      acc[3] = fmaf(qa, Ks[(j0 + 3) * 66 + c], acc[3]);
    }
  }
  constexpr float scale = 0.044194173824159216f;  // 1/sqrt(512)
#pragma unroll
  for (int jj = 0; jj < 4; ++jj) acc[jj] *= scale;
  float m = fmaxf(fmaxf(acc[0], acc[1]), fmaxf(acc[2], acc[3]));
  for (int off = 1; off < 8; off <<= 1) m = fmaxf(m, __shfl_xor(m, off));
  float e[4];
  float s = 0.f;
#pragma unroll
  for (int jj = 0; jj < 4; ++jj) {
    e[jj] = __expf(acc[jj] - m);
    s += e[jj];
  }
  for (int off = 1; off < 8; off <<= 1) s += __shfl_xor(s, off);
  const float inv = 1.f / s;
#pragma unroll
  for (int jj = 0; jj < 4; ++jj) Ps[i * 36 + j0 + jj] = e[jj] * inv;

  const int c_ = tid & 63;
  const int i4 = tid >> 6;
  for (int c0 = 0; c0 < kC; c0 += 64) {
    __syncthreads();
    {
      int r = tid >> 3, c8 = (tid & 7) * 8;
      bf16x8 vv = *(const bf16x8*)&v[((size_t)r * kHW + p) * kC + c0 + c8];
#pragma unroll
      for (int jj = 0; jj < 8; ++jj) Qs[r * 66 + c8 + jj] = bf2f(vv[jj]);
    }
    __syncthreads();
#pragma unroll
    for (int it = 0; it < 8; ++it) {
      const int ii = i4 + it * 4;
      float o = 0.f;
#pragma unroll
      for (int j = 0; j < 32; ++j)
        o = fmaf(Ps[ii * 36 + j], Qs[j * 66 + c_], o);
      virt[((size_t)ii * kHW + p) * kC + c0 + c_] = f2bf(o);
    }
  }
}

// ---- GroupNorm(1,C) stats per instance ------------------------------------
__global__ __launch_bounds__(1024) void gn_stats_kernel(
    const short* __restrict__ virt, float* __restrict__ stats) {
  const int i = blockIdx.x;
  const short* src = virt + (size_t)i * kHW * kC;
  float s = 0.f, sq = 0.f;
  for (int idx = threadIdx.x; idx < kHW * kC / 8; idx += 1024) {
    bf16x8 vv = *(const bf16x8*)&src[(size_t)idx * 8];
#pragma unroll
    for (int jj = 0; jj < 8; ++jj) {
      float f = bf2f(vv[jj]);
      s += f;
      sq = fmaf(f, f, sq);
    }
  }
  __shared__ float rs[16], rq[16];
  for (int off = 1; off < 64; off <<= 1) {
    s += __shfl_xor(s, off);
    sq += __shfl_xor(sq, off);
  }
  const int lane = threadIdx.x & 63;
  const int wid = threadIdx.x >> 6;
  if (lane == 0) { rs[wid] = s; rq[wid] = sq; }
  __syncthreads();
  if (threadIdx.x < 16) {
    s = rs[threadIdx.x];
    sq = rq[threadIdx.x];
    for (int off = 1; off < 16; off <<= 1) {
      s += __shfl_xor(s, off);
      sq += __shfl_xor(sq, off);
    }
    if (threadIdx.x == 0) {
      constexpr float invn = 1.f / ((float)kHW * kC);
      float mean = s * invn;
      float var = sq * invn - mean * mean;
      stats[i] = mean;
      stats[32 + i] = rsqrtf(var + 1e-5f);
    }
  }
}

// ---- GN apply + affine + ReLU -> chunked-padded bf16 ----------------------
__global__ __launch_bounds__(256) void gn_apply_kernel(
    const short* __restrict__ virt, const float* __restrict__ stats,
    const float* __restrict__ gamma, const float* __restrict__ beta,
    short* __restrict__ vh) {
  const size_t g = (size_t)blockIdx.x * 256 + threadIdx.x;
  const int i    = (int)(g >> 16);
  const int rest = (int)(g & 65535);
  const int p    = rest >> 6;
  const int c8g  = rest & 63;
  const int ci   = c8g * 8;
  const float mean = stats[i];
  const float rstd = stats[32 + i];
  bf16x8 vv = *(const bf16x8*)&virt[((size_t)i * kHW + p) * kC + ci];
  const float4 ga = ((const float4*)gamma)[c8g * 2];
  const float4 gb = ((const float4*)gamma)[c8g * 2 + 1];
  const float4 ba = ((const float4*)beta)[c8g * 2];
  const float4 bb = ((const float4*)beta)[c8g * 2 + 1];
  const float gv[8] = {ga.x, ga.y, ga.z, ga.w, gb.x, gb.y, gb.z, gb.w};
  const float bv[8] = {ba.x, ba.y, ba.z, ba.w, bb.x, bb.y, bb.z, bb.w};
  bf16x8 o;
#pragma unroll
  for (int jj = 0; jj < 8; ++jj) {
    float f = (bf2f(vv[jj]) - mean) * rstd;
    f = fmaxf(fmaf(f, gv[jj], bv[jj]), 0.f);
    o[jj] = f2bf(f);
  }
  const size_t dst =
      (((size_t)i * 16 + (ci >> 5)) * 1156 + (size_t)((p >> 5) + 1) * 34 + (p & 31) + 1) * 32
      + (ci & 31);
  *(bf16x8*)&vh[dst] = o;
}

}  // namespace

extern "C" void kernel_launch(void* const* d_in, const int* in_sizes, int n_in,
                              void* d_out, int out_size, void* d_ws,
                              size_t ws_size, hipStream_t stream) {
  const float* x     = (const float*)d_in[0];
  const float* w_q   = (const float*)d_in[1];
  const float* w_k   = (const float*)d_in[2];
  const float* w_v   = (const float*)d_in[3];
  const float* w_o   = (const float*)d_in[4];
  const float* gamma = (const float*)d_in[5];
  const float* beta  = (const float*)d_in[6];

  short* ws    = (short*)d_ws;
  short* wtf_q = ws;
  short* wtf_k = wtf_q + WTF_ELEMS;
  short* wtf_v = wtf_k + WTF_ELEMS;
  short* wtf_o = wtf_v + WTF_ELEMS;
  short* xh    = wtf_o + WTF_ELEMS;
  short* vh    = xh + XH_ELEMS;
  short* qb    = vh + XH_ELEMS;
  short* kb    = qb + QKV_ELEMS;
  short* vb    = kb + QKV_ELEMS;
  float* stats = (float*)(vb + QKV_ELEMS);
  short* virt  = qb;  // attn writes per-position after reading q
  // zero halos of xh and vh (adjacent regions)
  hipMemsetAsync(xh, 0, (size_t)2 * XH_ELEMS * sizeof(short), stream);

  dim3 wg(16, 16);
  wtf_pack_kernel<<<wg, 256, 0, stream>>>(w_q, wtf_q);
  wtf_pack_kernel<<<wg, 256, 0, stream>>>(w_k, wtf_k);
  wtf_pack_kernel<<<wg, 256, 0, stream>>>(w_v, wtf_v);
  wtf_pack_kernel<<<wg, 256, 0, stream>>>(w_o, wtf_o);

  x2xh_kernel<<<dim3(16, 32, 32), 256, 0, stream>>>(x, xh);

  conv_qkv_kernel<<<2048, 256, 0, stream>>>(xh, wtf_q, wtf_k, wtf_v,
                                            qb, kb, vb);

  attn_kernel<<<kHW, 256, 0, stream>>>(qb, kb, vb, virt);

  gn_stats_kernel<<<kN, 1024, 0, stream>>>(virt, stats);
  gn_apply_kernel<<<(int)(QKV_ELEMS / 8 / 256), 256, 0, stream>>>(
      virt, stats, gamma, beta, vh);

  conv_o_kernel<<<1024, 256, 0, stream>>>(vh, wtf_o, x, (float*)d_out);
}